// Round 1
// baseline (1198.493 us; speedup 1.0000x reference)
//
#include <hip/hip_runtime.h>

typedef _Float16 half8 __attribute__((ext_vector_type(8)));
typedef float f32x4 __attribute__((ext_vector_type(4)));

#define E_TOTAL 800000
#define EMBD 128
#define KDIM 384
#define NSLAB 12
#define WSTRIDE 40                    // halfs per W row in LDS (80 B, 16B-aligned, conflict-free)
#define SLAB_LDS (EMBD * WSTRIDE)     // 5120 halfs
#define WS_W_HALFS (KDIM * EMBD)      // 49152 halfs of W in workspace
#define N_TILES (E_TOTAL / 32)        // 25000 tiles of 32 edges
#define NBLOCKS 256
#define NWAVES (NBLOCKS * 8)          // 2048 waves, each grid-strides tiles

// ---- P: W_dense f32 [128][384] -> ws f16 slabs [12][128][32]; emb f32 [95][128] -> ws f16
__global__ __launch_bounds__(256) void prep_kernel(const float* __restrict__ Wd,
                                                   const float* __restrict__ emb,
                                                   _Float16* __restrict__ ws) {
    int id = blockIdx.x * 256 + threadIdx.x;
    if (id < WS_W_HALFS) {
        int n = id / KDIM, k = id - n * KDIM;      // n = out col, k = reduction dim
        ws[(k >> 5) * (EMBD * 32) + n * 32 + (k & 31)] = (_Float16)Wd[id];
    } else {
        int j = id - WS_W_HALFS;
        if (j < 95 * EMBD) ws[WS_W_HALFS + j] = (_Float16)emb[j];
    }
}

// ---- A: rbf_env = envelope(x) * sin(n*pi*x)/x, coalesced stores via LDS transpose
__global__ __launch_bounds__(256) void env_kernel(const float* __restrict__ d,
                                                  float* __restrict__ out1) {
    __shared__ float s[1536];
    const int tid = threadIdx.x;
    const int e = blockIdx.x * 256 + tid;
    float x = d[e] * 0.2f;                        // d / CUTOFF
    float inv = 1.0f / x;
    float x2 = x * x;
    float x5 = x2 * x2 * x;
    // p=6: 1/x - 28 x^5 + 48 x^6 - 21 x^7
    float env = inv + x5 * (-28.0f + x * (48.0f - 21.0f * x));
    float einv = env * inv;
    const float PI = 3.14159265358979323846f;
    float px = PI * x;
    #pragma unroll
    for (int n = 1; n <= 6; n++) s[tid * 6 + (n - 1)] = einv * __sinf(px * (float)n);
    __syncthreads();
    float4* ob = (float4*)(out1 + (size_t)blockIdx.x * 1536);
    const float4* sv = (const float4*)s;
    for (int k = tid; k < 384; k += 256) ob[k] = sv[k];
}

// ---- B: fused gather + rbf-proj + GEMM(E x 384 @ 384 x 128) + silu
// 512 threads = 8 waves; W resident in LDS (loaded once); A built in registers per wave;
// zero barriers in the steady-state loop.
__global__ __launch_bounds__(512) void main_kernel(
    const int* __restrict__ Z, const int* __restrict__ src, const int* __restrict__ dst,
    const float* __restrict__ rbf, const float* __restrict__ W_rbf,
    const float* __restrict__ b_rbf, const float* __restrict__ b_dense,
    const _Float16* __restrict__ ws, float* __restrict__ out0) {
    __shared__ _Float16 Wlds[NSLAB * SLAB_LDS];   // 122880 B
    __shared__ float s_wrbfT[7 * EMBD];           // rows 0..5: W_rbf^T, row 6: b_rbf
    __shared__ float s_bd[EMBD];

    const int tid = threadIdx.x;

    // stage full W into LDS with padded rows (one time)
    {
        const half8* sv = (const half8*)ws;       // 6144 chunks of 8 halfs
        for (int c = tid; c < 6144; c += 512) {
            half8 v = sv[c];
            int s = c >> 9, r = (c >> 2) & 127, q = c & 3;
            *(half8*)&Wlds[s * SLAB_LDS + r * WSTRIDE + q * 8] = v;
        }
    }
    for (int j = tid; j < 768; j += 512) {
        int c = j / 6, i = j - c * 6;
        s_wrbfT[i * EMBD + c] = W_rbf[j];
    }
    if (tid < EMBD) {
        s_wrbfT[6 * EMBD + tid] = b_rbf[tid];
        s_bd[tid] = b_dense[tid];
    }
    __syncthreads();                               // last barrier of the kernel

    const int w = tid >> 6;
    const int l = tid & 63;
    const int lr = l & 15;                         // row-in-tile (A) / col-in-tile (B,C)
    const int lg = l >> 4;                         // k-chunk group
    const int gw = blockIdx.x * 8 + w;             // global wave id 0..2047

    const half8* EB = (const half8*)(ws + WS_W_HALFS);   // emb f16, 16 half8 per row

    // first tile's node types (src -> Z chain primed before loop)
    int t = gw;
    int zsA, zdA, zsB, zdB;
    {
        int eA = t * 32 + lr;
        int iA = src[eA], jA = dst[eA], iB = src[eA + 16], jB = dst[eA + 16];
        zsA = Z[iA]; zdA = Z[jA]; zsB = Z[iB]; zdB = Z[jB];
    }

    for (; t < N_TILES; t += NWAVES) {
        const int eA = t * 32 + lr;
        // ---- A fragments: f16 emb gathers (L1-resident 24 KB table)
        half8 fa[12], fb[12];
        #pragma unroll
        for (int s4 = 0; s4 < 4; s4++) {
            fa[s4]     = EB[zsA * 16 + s4 * 4 + lg];
            fa[s4 + 4] = EB[zdA * 16 + s4 * 4 + lg];
            fb[s4]     = EB[zsB * 16 + s4 * 4 + lg];
            fb[s4 + 4] = EB[zdB * 16 + s4 * 4 + lg];
        }
        // rbf for both edges
        const float2* rpA = (const float2*)(rbf + (size_t)eA * 6);
        const float2* rpB = (const float2*)(rbf + (size_t)(eA + 16) * 6);
        float2 ra0 = rpA[0], ra1 = rpA[1], ra2 = rpA[2];
        float2 rb0 = rpB[0], rb1 = rpB[1], rb2 = rpB[2];
        float cra[6] = {ra0.x, ra0.y, ra1.x, ra1.y, ra2.x, ra2.y};
        float crb[6] = {rb0.x, rb0.y, rb1.x, rb1.y, rb2.x, rb2.y};

        // ---- prefetch next tile: src/dst now (latency hidden under rbf-proj VALU)
        const int t2 = t + NWAVES;
        const bool more = (t2 < N_TILES);
        int nsA = 0, ndA = 0, nsB = 0, ndB = 0;
        if (more) {
            int eA2 = t2 * 32 + lr;
            nsA = src[eA2]; ndA = dst[eA2]; nsB = src[eA2 + 16]; ndB = dst[eA2 + 16];
        }

        // ---- rbf projection + silu -> A fragments for k in [256,384)
        #pragma unroll
        for (int j4 = 0; j4 < 4; j4++) {
            #pragma unroll
            for (int jp = 0; jp < 4; jp++) {
                const int c = 32 * j4 + lg * 8 + jp * 2;
                float2 bb = *(const float2*)&s_wrbfT[6 * EMBD + c];
                float pA0 = bb.x, pA1 = bb.y, pB0 = bb.x, pB1 = bb.y;
                #pragma unroll
                for (int i = 0; i < 6; i++) {
                    float2 wv = *(const float2*)&s_wrbfT[i * EMBD + c];
                    pA0 += cra[i] * wv.x; pA1 += cra[i] * wv.y;
                    pB0 += crb[i] * wv.x; pB1 += crb[i] * wv.y;
                }
                pA0 *= __builtin_amdgcn_rcpf(1.0f + __expf(-pA0));
                pA1 *= __builtin_amdgcn_rcpf(1.0f + __expf(-pA1));
                pB0 *= __builtin_amdgcn_rcpf(1.0f + __expf(-pB0));
                pB1 *= __builtin_amdgcn_rcpf(1.0f + __expf(-pB1));
                fa[8 + j4][jp * 2]     = (_Float16)pA0;
                fa[8 + j4][jp * 2 + 1] = (_Float16)pA1;
                fb[8 + j4][jp * 2]     = (_Float16)pB0;
                fb[8 + j4][jp * 2 + 1] = (_Float16)pB1;
            }
        }

        // ---- prefetch next tile: Z (latency hidden under the MFMA block)
        if (more) { zsA = Z[nsA]; zdA = Z[ndA]; zsB = Z[nsB]; zdB = Z[ndB]; }

        // ---- GEMM: 12 slabs x 8 col-tiles; each B read feeds 2 MFMAs
        f32x4 acc0[8], acc1[8];
        #pragma unroll
        for (int i = 0; i < 8; i++) {
            acc0[i] = (f32x4){0.f, 0.f, 0.f, 0.f};
            acc1[i] = (f32x4){0.f, 0.f, 0.f, 0.f};
        }
        #pragma unroll
        for (int s = 0; s < NSLAB; s++) {
            const _Float16* wbase = &Wlds[s * SLAB_LDS + lg * 8];
            #pragma unroll
            for (int nt = 0; nt < 8; nt++) {
                half8 b = *(const half8*)&wbase[(nt * 16 + lr) * WSTRIDE];
                acc0[nt] = __builtin_amdgcn_mfma_f32_16x16x32_f16(fa[s], b, acc0[nt], 0, 0, 0);
                acc1[nt] = __builtin_amdgcn_mfma_f32_16x16x32_f16(fb[s], b, acc1[nt], 0, 0, 0);
            }
        }

        // ---- epilogue: bias + silu, fp32 stores (16 lanes -> 64 B contiguous per store)
        const int rbase = t * 32 + lg * 4;
        #pragma unroll
        for (int nt = 0; nt < 8; nt++) {
            const int col = nt * 16 + lr;
            const float bd = s_bd[col];
            #pragma unroll
            for (int r = 0; r < 4; r++) {
                float v = acc0[nt][r] + bd;
                v *= __builtin_amdgcn_rcpf(1.0f + __expf(-v));
                out0[(size_t)(rbase + r) * EMBD + col] = v;
                float u = acc1[nt][r] + bd;
                u *= __builtin_amdgcn_rcpf(1.0f + __expf(-u));
                out0[(size_t)(rbase + 16 + r) * EMBD + col] = u;
            }
        }
    }
}

extern "C" void kernel_launch(void* const* d_in, const int* in_sizes, int n_in,
                              void* d_out, int out_size, void* d_ws, size_t ws_size,
                              hipStream_t stream) {
    const int* Z = (const int*)d_in[0];
    const int* src = (const int*)d_in[1];
    const int* dst = (const int*)d_in[2];
    const float* rbf = (const float*)d_in[3];
    const float* dvec = (const float*)d_in[4];
    const float* emb = (const float*)d_in[5];
    const float* W_rbf = (const float*)d_in[6];
    const float* b_rbf = (const float*)d_in[7];
    const float* W_dense = (const float*)d_in[8];
    const float* b_dense = (const float*)d_in[9];

    float* out0 = (float*)d_out;
    float* out1 = out0 + (size_t)E_TOTAL * EMBD;
    _Float16* wsH = (_Float16*)d_ws;   // 49152 (W f16) + 12160 (emb f16) halfs = 122624 B

    prep_kernel<<<240, 256, 0, stream>>>(W_dense, emb, wsH);
    env_kernel<<<E_TOTAL / 256, 256, 0, stream>>>(dvec, out1);
    main_kernel<<<NBLOCKS, 512, 0, stream>>>(Z, src, dst, rbf, W_rbf, b_rbf, b_dense,
                                             wsH, out0);
}